// Round 5
// baseline (555.904 us; speedup 1.0000x reference)
//
#include <hip/hip_runtime.h>
#include <stdint.h>

#define NN 50000
#define EE 800000
#define NROWS 50048  // 782 * 64

typedef unsigned int u32;
typedef unsigned short u16;
using f32x4 = __attribute__((ext_vector_type(4))) float;
using short8 = __attribute__((ext_vector_type(8))) short;

__device__ __forceinline__ float bflo(u32 u) { return __uint_as_float(u << 16); }
__device__ __forceinline__ float bfhi(u32 u) { return __uint_as_float(u & 0xFFFF0000u); }
__device__ __forceinline__ float bf1(u16 v) { return __uint_as_float(((u32)v) << 16); }
__device__ __forceinline__ u32 f2bf(float f) {
    u32 u = __float_as_uint(f);
    return (u + 0x7FFFu + ((u >> 16) & 1u)) >> 16;
}
__device__ __forceinline__ u32 pack2(float lo, float hi) {
    return f2bf(lo) | (f2bf(hi) << 16);
}

// ---------- dtype detection: flag=1 if inputs are f32, 0 if bf16 ----------

__global__ void detect_kernel(const u32* __restrict__ xw, int* __restrict__ flag) {
    int tid = threadIdx.x;
    int cnt = 0;
    for (int i = tid; i < 8192; i += 256) {
        u32 u = xw[i];
        int e0 = (u >> 7) & 0xFF, e1 = (u >> 23) & 0xFF;
        cnt += (e0 >= 0xC3) + (e1 >= 0xC3);
    }
    #pragma unroll
    for (int off = 32; off; off >>= 1) cnt += __shfl_xor(cnt, off, 64);
    __shared__ int wsum[4];
    if ((tid & 63) == 0) wsum[tid >> 6] = cnt;
    __syncthreads();
    if (tid == 0) flag[0] = (wsum[0] + wsum[1] + wsum[2] + wsum[3] > 100) ? 1 : 0;
}

// ---------- degree / norm setup ----------

__global__ void count_deg_kernel(const int* __restrict__ ei, int* __restrict__ deg) {
    int e = blockIdx.x * 256 + threadIdx.x;
    if (e < EE) atomicAdd(&deg[ei[EE + e]], 1);
}

// scan phase 1 (+ dinv fused)
__global__ void scan1_kernel(const int* __restrict__ deg, int* __restrict__ excl,
                             int* __restrict__ bsum, float* __restrict__ dinv) {
    int i = blockIdx.x * 256 + threadIdx.x;
    int lane = threadIdx.x & 63, w = threadIdx.x >> 6;
    int v = (i < NN) ? deg[i] : 0;
    if (i < NN) dinv[i] = v > 0 ? rsqrtf((float)v) : 0.f;
    int x = v;
    #pragma unroll
    for (int off = 1; off < 64; off <<= 1) {
        int y = __shfl_up(x, off, 64);
        if (lane >= off) x += y;
    }
    __shared__ int ws[4];
    if (lane == 63) ws[w] = x;
    __syncthreads();
    int add = 0;
    if (w > 0) add += ws[0];
    if (w > 1) add += ws[1];
    if (w > 2) add += ws[2];
    if (i < NN) excl[i] = x - v + add;
    if (threadIdx.x == 255) bsum[blockIdx.x] = x + add;
}

__global__ void scan2_kernel(int* __restrict__ bsum, int* __restrict__ boff, int nb) {
    int tid = threadIdx.x, lane = tid & 63, w = tid >> 6;
    int v = (tid < nb) ? bsum[tid] : 0;
    int x = v;
    #pragma unroll
    for (int off = 1; off < 64; off <<= 1) {
        int y = __shfl_up(x, off, 64);
        if (lane >= off) x += y;
    }
    __shared__ int ws[4];
    if (lane == 63) ws[w] = x;
    __syncthreads();
    int add = 0;
    if (w > 0) add += ws[0];
    if (w > 1) add += ws[1];
    if (w > 2) add += ws[2];
    if (tid < nb) boff[tid] = x - v + add;
}

__global__ void scan3_kernel(int* __restrict__ rowptr, const int* __restrict__ boff,
                             int* __restrict__ woff) {
    int i = blockIdx.x * 256 + threadIdx.x;
    if (i < NN) {
        int r = rowptr[i] + boff[blockIdx.x];
        rowptr[i] = r;
        woff[i] = r;
    }
    if (i == 0) rowptr[NN] = EE;
}

// erec[p] = {src, norm} bucketed by target
__global__ void bucket_kernel(const int* __restrict__ ei, const float* __restrict__ dinv,
                              int* __restrict__ woff, int2* __restrict__ erec) {
    int e = blockIdx.x * 256 + threadIdx.x;
    if (e >= EE) return;
    int r = ei[e], c = ei[EE + e];
    int p = atomicAdd(&woff[c], 1);
    erec[p] = make_int2(r, __float_as_int(dinv[r] * dinv[c]));
}

// ---------- weight prep: W [4][128][fout] -> WT bf16 [fout][512] ----------

__global__ void wprep_kernel(const void* __restrict__ w, u16* __restrict__ wt,
                             int fout, int total, const int* __restrict__ flag) {
    int idx = blockIdx.x * 256 + threadIdx.x;
    if (idx >= total) return;
    u16 v = flag[0] ? (u16)f2bf(((const float*)w)[idx]) : ((const u16*)w)[idx];
    int per = 128 * fout;
    int k = idx / per, rem = idx % per;
    int in = rem / fout, o = rem % fout;
    wt[(size_t)o * 512 + k * 128 + in] = v;
}

__global__ void bprep_kernel(const void* __restrict__ b1, const void* __restrict__ b2,
                             float* __restrict__ bf, const int* __restrict__ flag) {
    int i = threadIdx.x;  // 192 threads
    if (i < 128) bf[i] = flag[0] ? ((const float*)b1)[i] : bf1(((const u16*)b1)[i]);
    else {
        int j = i - 128;
        bf[i] = flag[0] ? ((const float*)b2)[j] : bf1(((const u16*)b2)[j]);
    }
}

__global__ void import_x_kernel(const void* __restrict__ x, u32* __restrict__ h,
                                const int* __restrict__ flag) {
    int i = blockIdx.x * 256 + threadIdx.x;
    if (i >= NN * 64) return;
    if (flag[0]) {
        const float* xf = (const float*)x;
        h[i] = pack2(xf[2 * i], xf[2 * i + 1]);
    } else {
        h[i] = ((const u32*)x)[i];
    }
}

// ---------- propagation: one block (4 waves) per node ----------

__global__ __launch_bounds__(256) void prop_kernel(const u32* __restrict__ hin,
                                                   u32* __restrict__ hout,
                                                   const int* __restrict__ rowptr,
                                                   const int2* __restrict__ erec) {
    __shared__ float red[3][64][2];
    int node = blockIdx.x;
    int wid = threadIdx.x >> 6, lane = threadIdx.x & 63;
    int e0 = rowptr[node], e1 = rowptr[node + 1];
    float ax = 0.f, ay = 0.f;
    for (int base = e0 + wid * 4; base < e1; base += 16) {
        int2 r = make_int2(0, 0);  // src=0 (valid row), norm=0.0f (no contribution)
        if (lane < 4 && base + lane < e1) r = erec[base + lane];
        #pragma unroll
        for (int u = 0; u < 4; u++) {
            int s = __builtin_amdgcn_readlane(r.x, u);
            float wgt = __uint_as_float((u32)__builtin_amdgcn_readlane(r.y, u));
            u32 hv = hin[(size_t)s * 64 + lane];
            ax = fmaf(wgt, bflo(hv), ax);
            ay = fmaf(wgt, bfhi(hv), ay);
        }
    }
    if (wid) { red[wid - 1][lane][0] = ax; red[wid - 1][lane][1] = ay; }
    __syncthreads();
    if (wid == 0) {
        #pragma unroll
        for (int t = 0; t < 3; t++) { ax += red[t][lane][0]; ay += red[t][lane][1]; }
        hout[(size_t)node * 64 + lane] = pack2(ax, ay);
    }
}

// ---------- MFMA GEMM, K=512 over 4 hop-buffers ----------

__device__ __forceinline__ short8 ld8(const void* p) {
    return __builtin_bit_cast(short8, *(const uint4*)p);
}

// one hop's worth of K (128), loads batched BQ q-steps at a time
template <int NT, int BQ>
__device__ __forceinline__ void hop_step(const u32* __restrict__ buf,
                                         const u16* __restrict__ wtc,
                                         int row, int lane, int hop, f32x4* acc) {
    int qo = lane >> 4, cl = lane & 15;
    #pragma unroll
    for (int qb = 0; qb < 4; qb += BQ) {
        short8 a[BQ];
        short8 b[BQ][NT];
        #pragma unroll
        for (int i = 0; i < BQ; i++) {
            int q = qb + i;
            a[i] = ld8(buf + (size_t)row * 64 + q * 16 + qo * 4);
            #pragma unroll
            for (int t = 0; t < NT; t++)
                b[i][t] = ld8(wtc + (size_t)(16 * t + cl) * 512 + hop * 128 + q * 32 + qo * 8);
        }
        #pragma unroll
        for (int i = 0; i < BQ; i++) {
            #pragma unroll
            for (int t = 0; t < NT; t++)
                acc[t] = __builtin_amdgcn_mfma_f32_16x16x32_bf16(a[i], b[i][t], acc[t], 0, 0, 0);
        }
    }
}

// layer 1: out = relu(sum_k h_k @ W1[k] + b1) -> bf16 [N,128]
// NT=4: col-split across blockIdx.y (out must NOT alias inputs)
// NT=8: single col group (out may alias h0: each wave reads only its own 16 rows)
template <int NT, int BQ>
__global__ __launch_bounds__(256) void gemm1_kernel(const u32* __restrict__ h0,
                                                    const u32* __restrict__ h1,
                                                    const u32* __restrict__ h2,
                                                    const u32* __restrict__ h3,
                                                    const u16* __restrict__ wt,
                                                    const float* __restrict__ bias,
                                                    u32* __restrict__ hout) {
    int lane = threadIdx.x & 63, w = threadIdx.x >> 6;
    int rw = blockIdx.x * 64 + 16 * w;
    int row = rw + (lane & 15);
    int cb = blockIdx.y * 16 * NT;
    const u16* wtc = wt + (size_t)cb * 512;
    f32x4 acc[NT];
    #pragma unroll
    for (int t = 0; t < NT; t++) acc[t] = (f32x4){0.f, 0.f, 0.f, 0.f};
    hop_step<NT, BQ>(h0, wtc, row, lane, 0, acc);
    hop_step<NT, BQ>(h1, wtc, row, lane, 1, acc);
    hop_step<NT, BQ>(h2, wtc, row, lane, 2, acc);
    hop_step<NT, BQ>(h3, wtc, row, lane, 3, acc);
    int r0 = rw + (lane >> 4) * 4;
    int col = lane & 15;
    u16* o = (u16*)hout;
    #pragma unroll
    for (int t = 0; t < NT; t++) {
        float bs = bias[cb + 16 * t + col];
        #pragma unroll
        for (int r = 0; r < 4; r++) {
            int rr = r0 + r;
            if (rr < NN)
                o[(size_t)rr * 128 + cb + 16 * t + col] = (u16)f2bf(fmaxf(acc[t][r] + bs, 0.f));
        }
    }
}

// layer 2: out = log_softmax(sum_k g_k @ W2[k] + b2) -> d_out
__global__ __launch_bounds__(256) void gemm2_kernel(const u32* __restrict__ g0,
                                                    const u32* __restrict__ g1,
                                                    const u32* __restrict__ g2,
                                                    const u32* __restrict__ g3,
                                                    const u16* __restrict__ wt,
                                                    const float* __restrict__ bias,
                                                    void* __restrict__ outv,
                                                    const int* __restrict__ flag) {
    int lane = threadIdx.x & 63, w = threadIdx.x >> 6;
    int rw = blockIdx.x * 64 + 16 * w;
    int row = rw + (lane & 15);
    f32x4 acc[4];
    #pragma unroll
    for (int t = 0; t < 4; t++) acc[t] = (f32x4){0.f, 0.f, 0.f, 0.f};
    hop_step<4, 4>(g0, wt, row, lane, 0, acc);
    hop_step<4, 4>(g1, wt, row, lane, 1, acc);
    hop_step<4, 4>(g2, wt, row, lane, 2, acc);
    hop_step<4, 4>(g3, wt, row, lane, 3, acc);
    int col = lane & 15;
    float bs0 = bias[col], bs1 = bias[16 + col], bs2 = bias[32 + col], bs3 = bias[48 + col];
    int r0 = rw + (lane >> 4) * 4;
    int fl = flag[0];
    #pragma unroll
    for (int r = 0; r < 4; r++) {
        float v0 = acc[0][r] + bs0, v1 = acc[1][r] + bs1;
        float v2 = acc[2][r] + bs2, v3 = acc[3][r] + bs3;
        float m = fmaxf(fmaxf(v0, v1), fmaxf(v2, v3));
        #pragma unroll
        for (int msk = 8; msk; msk >>= 1) m = fmaxf(m, __shfl_xor(m, msk, 64));
        float s = __expf(v0 - m) + __expf(v1 - m) + __expf(v2 - m) + __expf(v3 - m);
        #pragma unroll
        for (int msk = 8; msk; msk >>= 1) s += __shfl_xor(s, msk, 64);
        float lg = m + __logf(s);
        int rr = r0 + r;
        if (rr < NN) {
            size_t bidx = (size_t)rr * 64 + col;
            if (fl) {
                float* of = (float*)outv;
                of[bidx] = v0 - lg;
                of[bidx + 16] = v1 - lg;
                of[bidx + 32] = v2 - lg;
                of[bidx + 48] = v3 - lg;
            } else {
                u16* ob = (u16*)outv;
                ob[bidx] = (u16)f2bf(v0 - lg);
                ob[bidx + 16] = (u16)f2bf(v1 - lg);
                ob[bidx + 32] = (u16)f2bf(v2 - lg);
                ob[bidx + 48] = (u16)f2bf(v3 - lg);
            }
        }
    }
}

// ---------- launch ----------

extern "C" void kernel_launch(void* const* d_in, const int* in_sizes, int n_in,
                              void* d_out, int out_size, void* d_ws, size_t ws_size,
                              hipStream_t stream) {
    const void* x  = d_in[0];
    const int*  ei = (const int*)d_in[1];
    const void* W1 = d_in[2];
    const void* b1 = d_in[3];
    const void* W2 = d_in[4];
    const void* b2 = d_in[5];

    char* ws = (char*)d_ws;
    size_t p = 0;
    auto alloc = [&](size_t bytes) -> void* {
        void* r = ws + p;
        p = (p + bytes + 255) & ~(size_t)255;
        return r;
    };
    int*   flag   = (int*)  alloc(256);
    int*   deg    = (int*)  alloc((size_t)NN * 4);
    float* dinv   = (float*)alloc((size_t)NN * 4);
    int*   rowptr = (int*)  alloc((size_t)(NN + 1) * 4);
    int*   woff   = (int*)  alloc((size_t)NN * 4);
    int*   bsum   = (int*)  alloc(256 * 4);
    int*   boff   = (int*)  alloc(256 * 4);
    int2*  erec   = (int2*) alloc((size_t)EE * 8);
    u16*   wt1    = (u16*)  alloc((size_t)128 * 512 * 2);
    u16*   wt2    = (u16*)  alloc((size_t)64 * 512 * 2);
    float* biasF  = (float*)alloc(192 * 4);
    const size_t hbytes = (size_t)(NROWS + 16) * 64 * 4;
    u32*   hA     = (u32*)  alloc(hbytes);
    u32*   hB     = (u32*)  alloc(hbytes);
    u32*   hC     = (u32*)  alloc(hbytes);
    u32*   hD     = (u32*)  alloc(hbytes);
    // base total ~= 58.5 MB; hE (+12.8 MB) only if workspace allows
    int colsplit = (p + hbytes + 256 <= ws_size) ? 1 : 0;
    u32* hE = colsplit ? (u32*)alloc(hbytes) : hA;

    const int NB = (NN + 255) / 256;  // 196

    hipMemsetAsync(deg, 0, (size_t)NN * 4, stream);
    detect_kernel<<<1, 256, 0, stream>>>((const u32*)x, flag);
    count_deg_kernel<<<(EE + 255) / 256, 256, 0, stream>>>(ei, deg);
    scan1_kernel<<<NB, 256, 0, stream>>>(deg, rowptr, bsum, dinv);
    scan2_kernel<<<1, 256, 0, stream>>>(bsum, boff, NB);
    scan3_kernel<<<NB, 256, 0, stream>>>(rowptr, boff, woff);
    bucket_kernel<<<(EE + 255) / 256, 256, 0, stream>>>(ei, dinv, woff, erec);
    wprep_kernel<<<(4 * 128 * 128 + 255) / 256, 256, 0, stream>>>(W1, wt1, 128, 4 * 128 * 128, flag);
    wprep_kernel<<<(4 * 128 * 64 + 255) / 256, 256, 0, stream>>>(W2, wt2, 64, 4 * 128 * 64, flag);
    bprep_kernel<<<1, 192, 0, stream>>>(b1, b2, biasF, flag);

    const int IG = (NN * 64) / 256;   // import grid
    const int GG = NROWS / 64;        // 782

    import_x_kernel<<<IG, 256, 0, stream>>>(x, hA, flag);

    // layer 1: h_k = A^k x; fused GEMM + bias + relu
    prop_kernel<<<NN, 256, 0, stream>>>(hA, hB, rowptr, erec);
    prop_kernel<<<NN, 256, 0, stream>>>(hB, hC, rowptr, erec);
    prop_kernel<<<NN, 256, 0, stream>>>(hC, hD, rowptr, erec);
    if (colsplit)
        gemm1_kernel<4, 4><<<dim3(GG, 2), 256, 0, stream>>>(hA, hB, hC, hD, wt1, biasF, hE);
    else
        gemm1_kernel<8, 2><<<dim3(GG, 1), 256, 0, stream>>>(hA, hB, hC, hD, wt1, biasF, hA);

    // layer 2: g_k = A^k h; fused GEMM + bias + log_softmax -> d_out
    prop_kernel<<<NN, 256, 0, stream>>>(hE, hB, rowptr, erec);
    prop_kernel<<<NN, 256, 0, stream>>>(hB, hC, rowptr, erec);
    prop_kernel<<<NN, 256, 0, stream>>>(hC, hD, rowptr, erec);
    gemm2_kernel<<<GG, 256, 0, stream>>>(hE, hB, hC, hD, wt2, biasF + 128, d_out, flag);
}

// Round 6
// 414.048 us; speedup vs baseline: 1.3426x; 1.3426x over previous
//
#include <hip/hip_runtime.h>
#include <stdint.h>

#define NN 50000
#define EE 800000
#define NROWS 50048  // 782 * 64

typedef unsigned int u32;
typedef unsigned short u16;
using f32x4 = __attribute__((ext_vector_type(4))) float;
using short8 = __attribute__((ext_vector_type(8))) short;

__device__ __forceinline__ float bflo(u32 u) { return __uint_as_float(u << 16); }
__device__ __forceinline__ float bfhi(u32 u) { return __uint_as_float(u & 0xFFFF0000u); }
__device__ __forceinline__ float bf1(u16 v) { return __uint_as_float(((u32)v) << 16); }
__device__ __forceinline__ u32 f2bf(float f) {
    u32 u = __float_as_uint(f);
    return (u + 0x7FFFu + ((u >> 16) & 1u)) >> 16;
}
__device__ __forceinline__ u32 pack2(float lo, float hi) {
    return f2bf(lo) | (f2bf(hi) << 16);
}

// ---------- dtype detection: flag=1 if inputs are f32, 0 if bf16 ----------

__global__ void detect_kernel(const u32* __restrict__ xw, int* __restrict__ flag) {
    int tid = threadIdx.x;
    int cnt = 0;
    for (int i = tid; i < 8192; i += 256) {
        u32 u = xw[i];
        int e0 = (u >> 7) & 0xFF, e1 = (u >> 23) & 0xFF;
        cnt += (e0 >= 0xC3) + (e1 >= 0xC3);
    }
    #pragma unroll
    for (int off = 32; off; off >>= 1) cnt += __shfl_xor(cnt, off, 64);
    __shared__ int wsum[4];
    if ((tid & 63) == 0) wsum[tid >> 6] = cnt;
    __syncthreads();
    if (tid == 0) flag[0] = (wsum[0] + wsum[1] + wsum[2] + wsum[3] > 100) ? 1 : 0;
}

// ---------- degree / norm / CSR setup ----------

__global__ void count_deg_kernel(const int* __restrict__ ei, int* __restrict__ deg) {
    int e = blockIdx.x * 256 + threadIdx.x;
    if (e < EE) atomicAdd(&deg[ei[EE + e]], 1);
}

__global__ void scan1_kernel(const int* __restrict__ deg, int* __restrict__ excl,
                             int* __restrict__ bsum, float* __restrict__ dinv) {
    int i = blockIdx.x * 256 + threadIdx.x;
    int lane = threadIdx.x & 63, w = threadIdx.x >> 6;
    int v = (i < NN) ? deg[i] : 0;
    if (i < NN) dinv[i] = v > 0 ? rsqrtf((float)v) : 0.f;
    int x = v;
    #pragma unroll
    for (int off = 1; off < 64; off <<= 1) {
        int y = __shfl_up(x, off, 64);
        if (lane >= off) x += y;
    }
    __shared__ int ws[4];
    if (lane == 63) ws[w] = x;
    __syncthreads();
    int add = 0;
    if (w > 0) add += ws[0];
    if (w > 1) add += ws[1];
    if (w > 2) add += ws[2];
    if (i < NN) excl[i] = x - v + add;
    if (threadIdx.x == 255) bsum[blockIdx.x] = x + add;
}

__global__ void scan2_kernel(int* __restrict__ bsum, int* __restrict__ boff, int nb) {
    int tid = threadIdx.x, lane = tid & 63, w = tid >> 6;
    int v = (tid < nb) ? bsum[tid] : 0;
    int x = v;
    #pragma unroll
    for (int off = 1; off < 64; off <<= 1) {
        int y = __shfl_up(x, off, 64);
        if (lane >= off) x += y;
    }
    __shared__ int ws[4];
    if (lane == 63) ws[w] = x;
    __syncthreads();
    int add = 0;
    if (w > 0) add += ws[0];
    if (w > 1) add += ws[1];
    if (w > 2) add += ws[2];
    if (tid < nb) boff[tid] = x - v + add;
}

__global__ void scan3_kernel(int* __restrict__ rowptr, const int* __restrict__ boff,
                             int* __restrict__ woff) {
    int i = blockIdx.x * 256 + threadIdx.x;
    if (i < NN) {
        int r = rowptr[i] + boff[blockIdx.x];
        rowptr[i] = r;
        woff[i] = r;
    }
    if (i == 0) rowptr[NN] = EE;
}

__global__ void bucket_kernel(const int* __restrict__ ei, const float* __restrict__ dinv,
                              int* __restrict__ woff, int2* __restrict__ erec) {
    int e = blockIdx.x * 256 + threadIdx.x;
    if (e >= EE) return;
    int r = ei[e], c = ei[EE + e];
    int p = atomicAdd(&woff[c], 1);
    erec[p] = make_int2(r, __float_as_int(dinv[r] * dinv[c]));
}

// ---------- weight prep ----------
// mode 0: B[kk][col] with kk = k*128+in, col = o; chunk J = (kk>>3)*fout + o
// mode 1: B[in][c]  with c = k*fout+o (col-concat);  J = (in>>3)*(nk*fout) + k*fout + o
__global__ void wprep_kernel(const void* __restrict__ w, u16* __restrict__ wt,
                             int fout, int nk, int mode, int total,
                             const int* __restrict__ flag) {
    int idx = blockIdx.x * 256 + threadIdx.x;
    if (idx >= total) return;
    u16 v = flag[0] ? (u16)f2bf(((const float*)w)[idx]) : ((const u16*)w)[idx];
    int per = 128 * fout;
    int k = idx / per, rem = idx % per;
    int in = rem / fout, o = rem % fout;
    size_t J;
    if (mode == 0) J = (size_t)(k * 16 + (in >> 3)) * fout + o;
    else J = (size_t)(in >> 3) * (nk * fout) + k * fout + o;
    wt[J * 8 + (in & 7)] = v;
}

__global__ void bprep_kernel(const void* __restrict__ b1, const void* __restrict__ b2,
                             float* __restrict__ bf, const int* __restrict__ flag) {
    int i = threadIdx.x;  // 192 threads
    if (i < 128) bf[i] = flag[0] ? ((const float*)b1)[i] : bf1(((const u16*)b1)[i]);
    else {
        int j = i - 128;
        bf[i] = flag[0] ? ((const float*)b2)[j] : bf1(((const u16*)b2)[j]);
    }
}

__global__ void import_x_kernel(const void* __restrict__ x, u32* __restrict__ h,
                                const int* __restrict__ flag) {
    int i = blockIdx.x * 256 + threadIdx.x;
    if (i >= NN * 64) return;
    if (flag[0]) {
        const float* xf = (const float*)x;
        h[i] = pack2(xf[2 * i], xf[2 * i + 1]);
    } else {
        h[i] = ((const u32*)x)[i];
    }
}

// ---------- prop 128-wide: one wave per node, 16-deep gather pipeline ----------

__global__ __launch_bounds__(256) void prop128_kernel(const u32* __restrict__ hin,
                                                      u32* __restrict__ hout,
                                                      const int* __restrict__ rowptr,
                                                      const int2* __restrict__ erec) {
    int node = (blockIdx.x * 256 + threadIdx.x) >> 6;
    int lane = threadIdx.x & 63;
    if (node >= NN) return;
    int e0 = rowptr[node], e1 = rowptr[node + 1];
    float ax = 0.f, ay = 0.f;
    for (int base = e0; base < e1; base += 64) {
        int2 r = make_int2(0, 0);  // src=0 (valid row), norm=0 (no contribution)
        if (base + lane < e1) r = erec[base + lane];
        int cnt = e1 - base;
        if (cnt > 64) cnt = 64;
        for (int j = 0; j < cnt; j += 16) {
            u32 hv[16];
            float wg[16];
            #pragma unroll
            for (int u = 0; u < 16; u++) {
                int s = __builtin_amdgcn_readlane(r.x, j + u);
                wg[u] = __uint_as_float((u32)__builtin_amdgcn_readlane(r.y, j + u));
                hv[u] = hin[(size_t)s * 64 + lane];
            }
            #pragma unroll
            for (int u = 0; u < 16; u++) {
                ax = fmaf(wg[u], bflo(hv[u]), ax);
                ay = fmaf(wg[u], bfhi(hv[u]), ay);
            }
        }
    }
    hout[(size_t)node * 64 + lane] = pack2(ax, ay);
}

// ---------- prop 64-wide (Horner step): out = addend + A*in; FINAL adds bias+lsm ----------

__device__ __forceinline__ float gather64(const u16* __restrict__ hin, int e0, int e1,
                                          int lane, const int2* __restrict__ erec) {
    float a = 0.f;
    for (int base = e0; base < e1; base += 64) {
        int2 r = make_int2(0, 0);
        if (base + lane < e1) r = erec[base + lane];
        int cnt = e1 - base;
        if (cnt > 64) cnt = 64;
        for (int j = 0; j < cnt; j += 16) {
            float hv[16], wg[16];
            #pragma unroll
            for (int u = 0; u < 16; u++) {
                int s = __builtin_amdgcn_readlane(r.x, j + u);
                wg[u] = __uint_as_float((u32)__builtin_amdgcn_readlane(r.y, j + u));
                hv[u] = bf1(hin[(size_t)s * 64 + lane]);
            }
            #pragma unroll
            for (int u = 0; u < 16; u++) a = fmaf(wg[u], hv[u], a);
        }
    }
    return a;
}

__global__ __launch_bounds__(256) void prop64_add_kernel(const u16* __restrict__ hin,
                                                         const u16* __restrict__ addend,
                                                         u16* __restrict__ hout,
                                                         const int* __restrict__ rowptr,
                                                         const int2* __restrict__ erec) {
    int node = (blockIdx.x * 256 + threadIdx.x) >> 6;
    int lane = threadIdx.x & 63;
    if (node >= NN) return;
    float a = gather64(hin, rowptr[node], rowptr[node + 1], lane, erec);
    a += bf1(addend[(size_t)node * 64 + lane]);
    hout[(size_t)node * 64 + lane] = (u16)f2bf(a);
}

__global__ __launch_bounds__(256) void prop64_final_kernel(const u16* __restrict__ hin,
                                                           const u16* __restrict__ z0,
                                                           const float* __restrict__ bias,
                                                           void* __restrict__ outv,
                                                           const int* __restrict__ rowptr,
                                                           const int2* __restrict__ erec,
                                                           const int* __restrict__ flag) {
    int node = (blockIdx.x * 256 + threadIdx.x) >> 6;
    int lane = threadIdx.x & 63;
    if (node >= NN) return;
    float v = gather64(hin, rowptr[node], rowptr[node + 1], lane, erec);
    v += bf1(z0[(size_t)node * 64 + lane]) + bias[lane];
    float m = v;
    #pragma unroll
    for (int off = 32; off; off >>= 1) m = fmaxf(m, __shfl_xor(m, off, 64));
    float e = __expf(v - m);
    float s = e;
    #pragma unroll
    for (int off = 32; off; off >>= 1) s += __shfl_xor(s, off, 64);
    float r = v - m - __logf(s);
    if (flag[0]) ((float*)outv)[(size_t)node * 64 + lane] = r;
    else ((u16*)outv)[(size_t)node * 64 + lane] = (u16)f2bf(r);
}

// ---------- MFMA GEMM: LDS-staged A (XOR-swizzled), B chunks [k8][col] ----------

__device__ __forceinline__ short8 ld8(const u16* p) {
    return __builtin_bit_cast(short8, *(const uint4*)p);
}

// MODE 0: out = relu(A@B + bias) -> bf16 linear [N,128] (outH; may alias inputs:
//          each block reads/writes only its own 64 rows; single col-group required)
// MODE 1: out -> 4 bf16 planes [N,64], plane = blockIdx.y (col-concat B)
template <int NHOP, int NT, int MODE>
__global__ __launch_bounds__(256) void gemm_kernel(const u32* __restrict__ a0,
                                                   const u32* __restrict__ a1,
                                                   const u32* __restrict__ a2,
                                                   const u32* __restrict__ a3,
                                                   const u16* __restrict__ wt, int ncol,
                                                   const float* __restrict__ bias,
                                                   u32* __restrict__ outH,
                                                   u16* __restrict__ zp0, u16* __restrict__ zp1,
                                                   u16* __restrict__ zp2, u16* __restrict__ zp3) {
    __shared__ uint4 hs[1024];  // 64 rows x 16 chunks, XOR-swizzled
    const u32* bufs[4] = {a0, a1, a2, a3};
    int t = threadIdx.x;
    int lane = t & 63, w = t >> 6;
    int row0 = blockIdx.x * 64;
    int cb = blockIdx.y * 16 * NT;
    int m = lane & 15, qo = lane >> 4;
    f32x4 acc[NT];
    #pragma unroll
    for (int tt = 0; tt < NT; tt++) acc[tt] = (f32x4){0.f, 0.f, 0.f, 0.f};

    uint4 p[4];
    {
        const uint4* src = (const uint4*)a0 + (size_t)row0 * 16;
        #pragma unroll
        for (int i = 0; i < 4; i++) p[i] = src[t + 256 * i];
    }
    #pragma unroll
    for (int hop = 0; hop < NHOP; hop++) {
        __syncthreads();
        #pragma unroll
        for (int i = 0; i < 4; i++) {
            int g = t + 256 * i;
            hs[(g >> 4) * 16 + ((g & 15) ^ ((g >> 4) & 15))] = p[i];
        }
        __syncthreads();
        if (hop + 1 < NHOP) {
            const uint4* src = (const uint4*)bufs[hop + 1] + (size_t)row0 * 16;
            #pragma unroll
            for (int i = 0; i < 4; i++) p[i] = src[t + 256 * i];
        }
        #pragma unroll
        for (int q = 0; q < 4; q++) {
            short8 a = __builtin_bit_cast(short8,
                hs[(16 * w + m) * 16 + ((q * 4 + qo) ^ m)]);
            short8 b[NT];
            #pragma unroll
            for (int tt = 0; tt < NT; tt++)
                b[tt] = ld8(wt + ((size_t)(hop * 16 + q * 4 + qo) * ncol + cb + 16 * tt + m) * 8);
            #pragma unroll
            for (int tt = 0; tt < NT; tt++)
                acc[tt] = __builtin_amdgcn_mfma_f32_16x16x32_bf16(a, b[tt], acc[tt], 0, 0, 0);
        }
    }

    int r0 = row0 + 16 * w + qo * 4;
    if (MODE == 0) {
        u16* o = (u16*)outH;
        #pragma unroll
        for (int tt = 0; tt < NT; tt++) {
            float bs = bias[cb + 16 * tt + m];
            #pragma unroll
            for (int r = 0; r < 4; r++) {
                int rr = r0 + r;
                if (rr < NN)
                    o[(size_t)rr * 128 + cb + 16 * tt + m] =
                        (u16)f2bf(fmaxf(acc[tt][r] + bs, 0.f));
            }
        }
    } else {
        u16* zp = (blockIdx.y == 0) ? zp0 : (blockIdx.y == 1) ? zp1
                  : (blockIdx.y == 2) ? zp2 : zp3;
        #pragma unroll
        for (int tt = 0; tt < NT; tt++) {
            #pragma unroll
            for (int r = 0; r < 4; r++) {
                int rr = r0 + r;
                if (rr < NN)
                    zp[(size_t)rr * 64 + 16 * tt + m] = (u16)f2bf(acc[tt][r]);
            }
        }
    }
}

// ---------- launch ----------

extern "C" void kernel_launch(void* const* d_in, const int* in_sizes, int n_in,
                              void* d_out, int out_size, void* d_ws, size_t ws_size,
                              hipStream_t stream) {
    const void* x  = d_in[0];
    const int*  ei = (const int*)d_in[1];
    const void* W1 = d_in[2];
    const void* b1 = d_in[3];
    const void* W2 = d_in[4];
    const void* b2 = d_in[5];

    char* ws = (char*)d_ws;
    size_t p = 0;
    auto alloc = [&](size_t bytes) -> void* {
        void* r = ws + p;
        p = (p + bytes + 255) & ~(size_t)255;
        return r;
    };
    int*   flag   = (int*)  alloc(256);
    int*   deg    = (int*)  alloc((size_t)NN * 4);
    float* dinv   = (float*)alloc((size_t)NN * 4);
    int*   rowptr = (int*)  alloc((size_t)(NN + 1) * 4);
    int*   woff   = (int*)  alloc((size_t)NN * 4);
    int*   bsum   = (int*)  alloc(256 * 4);
    int*   boff   = (int*)  alloc(256 * 4);
    int2*  erec   = (int2*) alloc((size_t)EE * 8);
    u16*   wt1    = (u16*)  alloc((size_t)64 * 128 * 16);   // 128 KB
    u16*   wt2    = (u16*)  alloc((size_t)16 * 256 * 16);   // 64 KB
    float* biasF  = (float*)alloc(192 * 4);
    const size_t hbytes = (size_t)(NROWS + 16) * 64 * 4;
    u32* hA = (u32*)alloc(hbytes);
    u32* hB = (u32*)alloc(hbytes);
    u32* hC = (u32*)alloc(hbytes);
    u32* hD = (u32*)alloc(hbytes);
    // ~58.7 MB total
    const size_t ZP = (size_t)(NROWS + 16) * 64;  // u16 elements per plane
    u16* z0 = (u16*)hB;
    u16* z1 = (u16*)hB + ZP;
    u16* z2 = (u16*)hC;
    u16* z3 = (u16*)hC + ZP;
    u16* t1 = (u16*)hD;
    u16* t2 = (u16*)hD + ZP;

    const int NB = (NN + 255) / 256;  // 196

    hipMemsetAsync(deg, 0, (size_t)NN * 4, stream);
    detect_kernel<<<1, 256, 0, stream>>>((const u32*)x, flag);
    count_deg_kernel<<<(EE + 255) / 256, 256, 0, stream>>>(ei, deg);
    scan1_kernel<<<NB, 256, 0, stream>>>(deg, rowptr, bsum, dinv);
    scan2_kernel<<<1, 256, 0, stream>>>(bsum, boff, NB);
    scan3_kernel<<<NB, 256, 0, stream>>>(rowptr, boff, woff);
    bucket_kernel<<<(EE + 255) / 256, 256, 0, stream>>>(ei, dinv, woff, erec);
    wprep_kernel<<<(4 * 128 * 128 + 255) / 256, 256, 0, stream>>>(
        W1, wt1, 128, 4, 0, 4 * 128 * 128, flag);
    wprep_kernel<<<(4 * 128 * 64 + 255) / 256, 256, 0, stream>>>(
        W2, wt2, 64, 4, 1, 4 * 128 * 64, flag);
    bprep_kernel<<<1, 192, 0, stream>>>(b1, b2, biasF, flag);

    const int PG = (NN * 64) / 256;  // 12500: one wave per node
    const int GG = NROWS / 64;       // 782

    import_x_kernel<<<PG, 256, 0, stream>>>(x, hA, flag);

    // layer 1: h_k = A^k x (k=0..3), then fused K=512 GEMM + bias + relu -> H (=hA)
    prop128_kernel<<<PG, 256, 0, stream>>>(hA, hB, rowptr, erec);
    prop128_kernel<<<PG, 256, 0, stream>>>(hB, hC, rowptr, erec);
    prop128_kernel<<<PG, 256, 0, stream>>>(hC, hD, rowptr, erec);
    gemm_kernel<4, 8, 0><<<dim3(GG, 1), 256, 0, stream>>>(
        hA, hB, hC, hD, wt1, 128, biasF, hA, nullptr, nullptr, nullptr, nullptr);

    // layer 2: Z = H @ [W2_0|W2_1|W2_2|W2_3]  (planes into hB, hC)
    gemm_kernel<1, 4, 1><<<dim3(GG, 4), 256, 0, stream>>>(
        hA, hA, hA, hA, wt2, 256, biasF, nullptr, z0, z1, z2, z3);

    // Horner: out = Z0 + A(Z1 + A(Z2 + A Z3)) + b2, then log_softmax
    prop64_add_kernel<<<PG, 256, 0, stream>>>(z3, z2, t1, rowptr, erec);
    prop64_add_kernel<<<PG, 256, 0, stream>>>(t1, z1, t2, rowptr, erec);
    prop64_final_kernel<<<PG, 256, 0, stream>>>(t2, z0, biasF + 128, d_out, rowptr, erec, flag);
}